// Round 4
// baseline (184.949 us; speedup 1.0000x reference)
//
#include <hip/hip_runtime.h>
#include <math.h>

// EdgeDetection: fused gray -> gauss3x3(sigma=0.8) -> scharr -> L2 mag, reflect-101
// R3: barrier-free wave-streaming. Each wave owns a 256-wide x 16-row strip,
// streams 20 input rows, keeps a 5-row ring of horizontally-reduced (hs,hd) in
// registers. Composite separable 5-taps (Gauss∘Scharr) as in R2. Horizontal
// halo via lane shuffles + one exec-masked halo load; no LDS, no __syncthreads.

#define IMG_H 1024
#define IMG_W 1024
#define SH 16            // output rows per wave strip
#define SW 256           // strip width = 64 lanes * 4 px

// 1D gaussian sigma=0.8 k=3: e=exp(-0.78125); W0=1/(1+2e), W1=e/(1+2e)
#define W0 0.52201125f
#define W1 0.23899437f
// composite smooth taps a = conv([3,10,3],[W1,W0,W1]) (symmetric 5-tap):
#define AV0 0.71698311f   // 3*W1
#define AV1 3.95597745f   // 3*W0 + 10*W1
#define AV2 6.65407872f   // 10*W0 + 6*W1
// composite deriv taps d = conv([-1,0,1],[W1,W0,W1]) = [-W1,-W0,0,W0,W1]

__device__ __forceinline__ float4 gray4(float4 r, float4 g, float4 b) {
    float4 o;
    o.x = 0.299f * r.x + 0.587f * g.x + 0.114f * b.x;
    o.y = 0.299f * r.y + 0.587f * g.y + 0.114f * b.y;
    o.z = 0.299f * r.z + 0.587f * g.z + 0.114f * b.z;
    o.w = 0.299f * r.w + 0.587f * g.w + 0.114f * b.w;
    return o;
}

__global__ __launch_bounds__(256)
void edge_kernel(const float* __restrict__ in, float* __restrict__ out, int B) {
    const int tid  = threadIdx.x;
    const int lane = tid & 63;
    const int gw   = blockIdx.x * 4 + (tid >> 6);

    // consecutive waves in a block = adjacent ys of the same xs (share 4 halo rows in L1/L2)
    const int ys = gw & 63;
    const int xs = (gw >> 6) & 3;
    const int b  = gw >> 8;

    const int x0 = xs * SW;
    const int y0 = ys * SH;
    const int cb = x0 + 4 * lane;

    const size_t plane = (size_t)IMG_H * IMG_W;
    const float* pr = in + (size_t)b * 3 * plane;
    const float* pg = pr + plane;
    const float* pb = pg + plane;
    float* po = out + (size_t)b * 3 * plane;

    // halo column address: lane0 -> left halo float4, others -> right halo float4
    int hx = (lane == 0) ? (x0 - 4) : (x0 + SW);
    hx = min(max(hx, 0), IMG_W - 4);

    float hs[5][4], hd[5][4];

    #pragma unroll
    for (int t = 0; t < SH + 4; ++t) {
        int yy = y0 - 2 + t;
        yy = (yy < 0) ? -yy : ((yy >= IMG_H) ? (2 * IMG_H - 2 - yy) : yy);
        const size_t ro = (size_t)yy << 10;

        float4 r4 = *(const float4*)(pr + ro + cb);
        float4 g4 = *(const float4*)(pg + ro + cb);
        float4 b4 = *(const float4*)(pb + ro + cb);
        float4 hr = *(const float4*)(pr + ro + hx);
        float4 hg = *(const float4*)(pg + ro + hx);
        float4 hb = *(const float4*)(pb + ro + hx);

        float4 g   = gray4(r4, g4, b4);
        float4 hgr = gray4(hr, hg, hb);

        // neighbor-lane exchange (wave-synchronous, no barrier)
        float lm2 = __shfl_up(g.z, 1);     // g[c-2]
        float lm1 = __shfl_up(g.w, 1);     // g[c-1]
        float rp1 = __shfl_down(g.x, 1);   // g[c+4]
        float rp2 = __shfl_down(g.y, 1);   // g[c+5]
        float rbx = __shfl(hgr.x, 1);      // lane1's right-halo g[x0+256]
        float rby = __shfl(hgr.y, 1);      // g[x0+257]

        // strip-edge fixups (branch-free):
        //  lane0 left: xs==0 -> image reflect (g[2],g[1]); else halo load (.z,.w)
        //  lane63 right: xs==3 -> image reflect (g[z],g[y]); else broadcast from lane1
        lm2 = (lane == 0)  ? ((xs == 0) ? g.z : hgr.z) : lm2;
        lm1 = (lane == 0)  ? ((xs == 0) ? g.y : hgr.w) : lm1;
        rp1 = (lane == 63) ? ((xs == 3) ? g.z : rbx)   : rp1;
        rp2 = (lane == 63) ? ((xs == 3) ? g.y : rby)   : rp2;

        const float G[8] = {lm2, lm1, g.x, g.y, g.z, g.w, rp1, rp2};
        const int ri = t % 5;
        #pragma unroll
        for (int k = 0; k < 4; ++k) {
            hs[ri][k] = AV0 * (G[k] + G[k+4]) + AV1 * (G[k+1] + G[k+3]) + AV2 * G[k+2];
            hd[ri][k] = W1 * (G[k+4] - G[k]) + W0 * (G[k+3] - G[k+1]);
        }

        if (t >= 4) {
            const int i0 = (t+1) % 5, i1 = (t+2) % 5, i2 = (t+3) % 5,
                      i3 = (t+4) % 5, i4 = t % 5;
            float4 mag;
            float* mp = &mag.x;
            #pragma unroll
            for (int k = 0; k < 4; ++k) {
                float sx = AV0 * (hd[i0][k] + hd[i4][k])
                         + AV1 * (hd[i1][k] + hd[i3][k])
                         + AV2 * hd[i2][k];
                float sy = W1 * (hs[i4][k] - hs[i0][k])
                         + W0 * (hs[i3][k] - hs[i1][k]);
                mp[k] = sqrtf(sx * sx + sy * sy);
            }
            size_t o = ((size_t)(y0 + t - 4) << 10) + cb;
            *(float4*)(po + o)             = mag;
            *(float4*)(po + o + plane)     = mag;
            *(float4*)(po + o + 2 * plane) = mag;
        }
    }
}

extern "C" void kernel_launch(void* const* d_in, const int* in_sizes, int n_in,
                              void* d_out, int out_size, void* d_ws, size_t ws_size,
                              hipStream_t stream) {
    const float* in = (const float*)d_in[0];
    float* out = (float*)d_out;
    const int B = in_sizes[0] / (3 * IMG_H * IMG_W);
    // waves: 4 xs * 64 ys * B; 4 waves per 256-thread block
    const int nblocks = (4 * 64 * B) / 4;
    edge_kernel<<<dim3(nblocks), dim3(256), 0, stream>>>(in, out, B);
}

// Round 5
// 179.551 us; speedup vs baseline: 1.0301x; 1.0301x over previous
//
#include <hip/hip_runtime.h>
#include <math.h>

// EdgeDetection: fused gray -> gauss3x3(sigma=0.8) -> scharr -> L2 mag, reflect-101
// R4: wave-streaming (no LDS, no barriers) with SH=4 strips (4x the waves of R3)
// and an explicit 2-row load pipeline so each wave keeps ~6KB of loads in flight.
// Composite separable 5-tap Gauss∘Scharr (identical math to R2/R3, which passed).

#define IMG_H 1024
#define IMG_W 1024
#define SH 4             // output rows per wave strip
#define SW 256           // strip width = 64 lanes * 4 px
#define NROWS (SH + 4)   // input rows streamed per strip

// 1D gaussian sigma=0.8 k=3: e=exp(-0.78125); W0=1/(1+2e), W1=e/(1+2e)
#define W0 0.52201125f
#define W1 0.23899437f
// composite smooth taps a = conv([3,10,3],[W1,W0,W1]) (symmetric 5-tap):
#define AV0 0.71698311f   // 3*W1
#define AV1 3.95597745f   // 3*W0 + 10*W1
#define AV2 6.65407872f   // 10*W0 + 6*W1
// composite deriv taps d = conv([-1,0,1],[W1,W0,W1]) = [-W1,-W0,0,W0,W1]

__device__ __forceinline__ float4 gray4(float4 r, float4 g, float4 b) {
    float4 o;
    o.x = 0.299f * r.x + 0.587f * g.x + 0.114f * b.x;
    o.y = 0.299f * r.y + 0.587f * g.y + 0.114f * b.y;
    o.z = 0.299f * r.z + 0.587f * g.z + 0.114f * b.z;
    o.w = 0.299f * r.w + 0.587f * g.w + 0.114f * b.w;
    return o;
}

__global__ __launch_bounds__(256, 4)
void edge_kernel(const float* __restrict__ in, float* __restrict__ out, int B) {
    const int tid  = threadIdx.x;
    const int lane = tid & 63;
    const int gw   = blockIdx.x * 4 + (tid >> 6);

    // low bits = ys: waves in a block (and nearby blocks) share vertical halo rows
    const int ys = gw & 255;
    const int xs = (gw >> 8) & 3;
    const int b  = gw >> 10;

    const int x0 = xs * SW;
    const int y0 = ys * SH;
    const int cb = x0 + 4 * lane;

    const size_t plane = (size_t)IMG_H * IMG_W;
    const float* pr  = in + (size_t)b * 3 * plane;
    const float* pg  = pr + plane;
    const float* pbl = pg + plane;
    float* po = out + (size_t)b * 3 * plane;

    // halo column: lane0 -> left halo float4; all other lanes -> right halo (uniform)
    int hx = (lane == 0) ? (x0 - 4) : (x0 + SW);
    hx = min(max(hx, 0), IMG_W - 4);

    auto rowoff = [&](int t) -> size_t {
        int yy = y0 - 2 + t;
        yy = (yy < 0) ? -yy : ((yy >= IMG_H) ? (2 * IMG_H - 2 - yy) : yy);
        return (size_t)yy << 10;
    };

    float4 cr[2], cg[2], cbv[2], chr[2], chg[2], chb[2];
    {
        size_t ro = rowoff(0);
        cr[0]  = *(const float4*)(pr  + ro + cb);
        cg[0]  = *(const float4*)(pg  + ro + cb);
        cbv[0] = *(const float4*)(pbl + ro + cb);
        chr[0] = *(const float4*)(pr  + ro + hx);
        chg[0] = *(const float4*)(pg  + ro + hx);
        chb[0] = *(const float4*)(pbl + ro + hx);
    }

    float hs[5][4], hd[5][4];

    #pragma unroll
    for (int t = 0; t < NROWS; ++t) {
        const int cu = t & 1, nx = cu ^ 1;
        // prefetch next row (independent of current-row consumption)
        if (t + 1 < NROWS) {
            size_t ro = rowoff(t + 1);
            cr[nx]  = *(const float4*)(pr  + ro + cb);
            cg[nx]  = *(const float4*)(pg  + ro + cb);
            cbv[nx] = *(const float4*)(pbl + ro + cb);
            chr[nx] = *(const float4*)(pr  + ro + hx);
            chg[nx] = *(const float4*)(pg  + ro + hx);
            chb[nx] = *(const float4*)(pbl + ro + hx);
        }

        float4 g   = gray4(cr[cu], cg[cu], cbv[cu]);
        float4 hgr = gray4(chr[cu], chg[cu], chb[cu]);

        // neighbor-lane exchange (wave-synchronous)
        float lm2 = __shfl_up(g.z, 1);     // g[c-2]
        float lm1 = __shfl_up(g.w, 1);     // g[c-1]
        float rp1 = __shfl_down(g.x, 1);   // g[c+4]
        float rp2 = __shfl_down(g.y, 1);   // g[c+5]
        float rbx = __shfl(hgr.x, 1);      // g[x0+256] (lane1's halo)
        float rby = __shfl(hgr.y, 1);      // g[x0+257]

        // strip-edge fixups (identical to R3, verified correct)
        lm2 = (lane == 0)  ? ((xs == 0) ? g.z : hgr.z) : lm2;
        lm1 = (lane == 0)  ? ((xs == 0) ? g.y : hgr.w) : lm1;
        rp1 = (lane == 63) ? ((xs == 3) ? g.z : rbx)   : rp1;
        rp2 = (lane == 63) ? ((xs == 3) ? g.y : rby)   : rp2;

        const float G[8] = {lm2, lm1, g.x, g.y, g.z, g.w, rp1, rp2};
        const int ri = t % 5;
        #pragma unroll
        for (int k = 0; k < 4; ++k) {
            hs[ri][k] = AV0 * (G[k] + G[k+4]) + AV1 * (G[k+1] + G[k+3]) + AV2 * G[k+2];
            hd[ri][k] = W1 * (G[k+4] - G[k]) + W0 * (G[k+3] - G[k+1]);
        }

        if (t >= 4) {
            const int i0 = (t+1) % 5, i1 = (t+2) % 5, i2 = (t+3) % 5,
                      i3 = (t+4) % 5, i4 = t % 5;
            float4 mag;
            float* mp = &mag.x;
            #pragma unroll
            for (int k = 0; k < 4; ++k) {
                float sx = AV0 * (hd[i0][k] + hd[i4][k])
                         + AV1 * (hd[i1][k] + hd[i3][k])
                         + AV2 * hd[i2][k];
                float sy = W1 * (hs[i4][k] - hs[i0][k])
                         + W0 * (hs[i3][k] - hs[i1][k]);
                mp[k] = sqrtf(sx * sx + sy * sy);
            }
            size_t o = ((size_t)(y0 + t - 4) << 10) + cb;
            *(float4*)(po + o)             = mag;
            *(float4*)(po + o + plane)     = mag;
            *(float4*)(po + o + 2 * plane) = mag;
        }
    }
}

extern "C" void kernel_launch(void* const* d_in, const int* in_sizes, int n_in,
                              void* d_out, int out_size, void* d_ws, size_t ws_size,
                              hipStream_t stream) {
    const float* in = (const float*)d_in[0];
    float* out = (float*)d_out;
    const int B = in_sizes[0] / (3 * IMG_H * IMG_W);
    // waves: 4 xs * 256 ys * B; 4 waves per 256-thread block
    const int nblocks = (4 * 256 * B) / 4;
    edge_kernel<<<dim3(nblocks), dim3(256), 0, stream>>>(in, out, B);
}